// Round 4
// baseline (116.820 us; speedup 1.0000x reference)
//
#include <hip/hip_runtime.h>

// B=8, Cin=64, H=W=128, Cout=64, 9 bilinear taps at (i+0.4, j+0.4) == exact 4x4
// conv with zero pad. Implicit GEMM, bf16 MFMA 32x32x16.
//
// v4: - mfma_f32_32x32x16_bf16 (halves LDS-A bytes per FLOP vs 16x16x32)
//     - B-weights bulk-prefetched into regs in 16KB chunks (no inner-loop
//       global scatter; each chunk = 16 coalesced 1KB lines)
//     - block = (batch, 4-row band, 64-px half): stage 7 halo rows once,
//       ONE barrier, then 256 barrier-free MFMAs/wave
//     - LDS 68.5KB -> 2 blocks/CU; staging of one block overlaps compute of
//       the other. Cell stride 72 shorts: 16B-group = (pos + c8) mod 8 ->
//       uniform 8 lanes/group (conflict-free minimum).

#define CIN   64
#define COUT  64
#define HH    128
#define WW    128

typedef __attribute__((ext_vector_type(8)))  short bf16x8;   // 4 VGPRs
typedef __attribute__((ext_vector_type(4)))  float f32x4;
typedef __attribute__((ext_vector_type(16))) float f32x16;   // 32x32 acc
typedef __attribute__((ext_vector_type(4)))  unsigned int u32x4;

__device__ __forceinline__ unsigned short f2bf(float f) {
  unsigned int u = __float_as_uint(f);
  u = (u + 0x7fffu + ((u >> 16) & 1u)) >> 16;   // RNE
  return (unsigned short)u;
}

// ---------------------------------------------------------------------------
// W4[o][c][tap(r,s)] = sum_k w[o,c,k]*cy_k(r-iy_k)*cx_k(s-ix_k).
// Layout for bulk B-prefetch: chunk (g = c>>4, h8 = tap>>3) is 16KB contiguous:
//   wb[(((g*2+h8)*16 + rs8*2 + ni)*64 + lane)*8 + j]
// consuming lane: o = ni*32 + (lane&31), ch = g*16 + (lane>>5)*8 + j, tap=h8*8+rs8.
// ---------------------------------------------------------------------------
__global__ void make_wb(const float* __restrict__ wgt,
                        const float* __restrict__ off,
                        unsigned short* __restrict__ wb)
{
  int id = blockIdx.x * 64 + threadIdx.x;       // 4096 = 64*64
  int o = id >> 6, c = id & 63;
  float W16[16];
  #pragma unroll
  for (int i = 0; i < 16; ++i) W16[i] = 0.f;
  for (int k = 0; k < 9; ++k) {
    float dy = off[2*k], dx = off[2*k+1];
    float fyf = floorf(dy), fxf = floorf(dx);
    int   iy = (int)fyf,   ix = (int)fxf;       // in {0,1,2}
    float fy = dy - fyf,   fx = dx - fxf;
    float wk = wgt[(o*CIN + c)*9 + k];
    W16[(iy  )*4 + ix  ] += wk * (1.f-fy)*(1.f-fx);
    W16[(iy  )*4 + ix+1] += wk * (1.f-fy)*fx;
    W16[(iy+1)*4 + ix  ] += wk * fy*(1.f-fx);
    W16[(iy+1)*4 + ix+1] += wk * fy*fx;
  }
  int g = c >> 4, half = (c >> 3) & 1, j = c & 7;
  int ni = o >> 5, l31 = o & 31;
  int lane = half*32 + l31;
  for (int tap = 0; tap < 16; ++tap) {
    int h8 = tap >> 3, rs8 = tap & 7;
    wb[(size_t)((((g*2 + h8)*16) + rs8*2 + ni)*64 + lane)*8 + j] = f2bf(W16[tap]);
  }
}

// ---------------------------------------------------------------------------
constexpr int CELL = 72;   // shorts per (row,pos) cell: 64ch + 8 pad = 144 B
constexpr int LPOS = 68;   // pos = gx - (x0-1), 0..66 used (+1 alloc pad)

__global__ __launch_bounds__(256, 2)          // 2 blocks/CU
void conv_mfma(const float* __restrict__ x,
               const unsigned short* __restrict__ wb,
               float* __restrict__ out)
{
  __shared__ unsigned short lt[7 * LPOS * CELL];   // 68544 B

  const int wg = blockIdx.x;                  // 512 = 8 b * 32 ybands * 2 xb
  const int b  = wg >> 6;
  const int y0 = ((wg >> 1) & 31) * 4;
  const int x0 = (wg & 1) * 64;
  const int t  = threadIdx.x;

  // ---- stage 7 x-rows (y0-1 .. y0+5) x 68 cols x 64 ch, bf16, once ----
  for (int id = t; id < 56 * LPOS; id += 256) {
    int cg  = id / LPOS;                      // row*8 + c8
    int pos = id - cg * LPOS;                 // 0..67
    int row = cg >> 3;                        // 0..6
    int c8  = cg & 7;                         // 8-channel chunk
    int gy  = y0 + row - 1;
    int gx  = x0 + pos - 1;
    bool ok = ((unsigned)gy < (unsigned)HH) && ((unsigned)gx < (unsigned)WW);
    int sgy = ok ? gy : 0, sgx = ok ? gx : 0;
    float sc = ok ? 1.f : 0.f;
    const float* ps = x + ((size_t)(b*CIN + c8*8)*HH + sgy)*WW + sgx;
    float v[8];
    #pragma unroll
    for (int cc = 0; cc < 8; ++cc) v[cc] = ps[(size_t)cc*HH*WW] * sc;
    unsigned int pk[4];
    #pragma unroll
    for (int i = 0; i < 4; ++i)
      pk[i] = (unsigned int)f2bf(v[2*i]) | ((unsigned int)f2bf(v[2*i+1]) << 16);
    *(u32x4*)&lt[(row*LPOS + pos)*CELL + c8*8] = *(u32x4*)pk;
  }
  __syncthreads();                            // the ONLY barrier

  // ---- compute: wave = output row y0+wave; M = 64px (2 frags), N = 64 (2) ----
  const int lane = t & 63;
  const int wave = t >> 6;                    // 0..3
  const int l31  = lane & 31;
  const int half = lane >> 5;

  f32x16 acc[2][2];
  #pragma unroll
  for (int xh = 0; xh < 2; ++xh)
    #pragma unroll
    for (int ni = 0; ni < 2; ++ni)
      acc[xh][ni] = (f32x16)(0.f);

  const unsigned short* wl = wb + lane*8;

  #pragma unroll
  for (int g = 0; g < 4; ++g) {               // 16-channel group
    #pragma unroll
    for (int h8 = 0; h8 < 2; ++h8) {          // tap half
      // bulk-prefetch this chunk's 16 B-fragments (16KB, coalesced lines)
      bf16x8 bfr[8][2];
      #pragma unroll
      for (int rs8 = 0; rs8 < 8; ++rs8)
        #pragma unroll
        for (int ni = 0; ni < 2; ++ni)
          bfr[rs8][ni] = *(const bf16x8*)(wl + (size_t)(((g*2 + h8)*16) + rs8*2 + ni)*512);
      #pragma unroll
      for (int rs8 = 0; rs8 < 8; ++rs8) {
        const int tap = h8*8 + rs8;
        const int r = tap >> 2, sx = tap & 3;
        #pragma unroll
        for (int xh = 0; xh < 2; ++xh) {
          bf16x8 afr = *(const bf16x8*)
            &lt[((wave + r)*LPOS + (xh*32 + l31 + sx))*CELL + g*16 + half*8];
          acc[xh][0] = __builtin_amdgcn_mfma_f32_32x32x16_bf16(afr, bfr[rs8][0], acc[xh][0], 0, 0, 0);
          acc[xh][1] = __builtin_amdgcn_mfma_f32_32x32x16_bf16(afr, bfr[rs8][1], acc[xh][1], 0, 0, 0);
        }
      }
    }
  }

  // ---- epilogue: D col = o (lane&31), row = (reg&3) + 8*(reg>>2) + 4*half ----
  const int y = y0 + wave;
  #pragma unroll
  for (int xh = 0; xh < 2; ++xh) {
    #pragma unroll
    for (int ni = 0; ni < 2; ++ni) {
      int o = ni*32 + l31;
      float* dst = out + (((size_t)(b*COUT + o))*HH + y)*WW + x0 + xh*32 + 4*half;
      #pragma unroll
      for (int rg = 0; rg < 4; ++rg) {
        f32x4 v = (f32x4){acc[xh][ni][4*rg+0], acc[xh][ni][4*rg+1],
                          acc[xh][ni][4*rg+2], acc[xh][ni][4*rg+3]};
        *(f32x4*)(dst + 8*rg) = v;
      }
    }
  }
}

// ---------------------------------------------------------------------------
extern "C" void kernel_launch(void* const* d_in, const int* in_sizes, int n_in,
                              void* d_out, int out_size, void* d_ws, size_t ws_size,
                              hipStream_t stream)
{
  const float* x   = (const float*)d_in[0];   // [8,64,128,128] fp32
  const float* wgt = (const float*)d_in[1];   // [64,64,9] fp32
  const float* off = (const float*)d_in[2];   // [9,2] fp32
  float* out = (float*)d_out;                 // [8,64,128,128] fp32
  unsigned short* wb = (unsigned short*)d_ws; // 128 KB chunked weights

  make_wb<<<64, 64, 0, stream>>>(wgt, off, wb);
  conv_mfma<<<512, 256, 0, stream>>>(x, wb, out);
}

// Round 5
// 116.152 us; speedup vs baseline: 1.0057x; 1.0057x over previous
//
#include <hip/hip_runtime.h>

// B=8, Cin=64, H=W=128, Cout=64, 9 bilinear taps at (i+0.4, j+0.4) == exact 4x4
// conv with zero pad. Implicit GEMM, bf16 MFMA 32x32x16.
//
// v5: v4 structure with disciplined resources.
//   - LDS tile = 7 rows x 68 pos x 32ch(+8 pad) = 38080 B -> 3 blocks/CU
//     (channel passes p=0,1; acc persists in 64 VGPRs)
//   - B double-buffered 2 taps at a time (16 VGPRs live, prefetch 1 iter ahead)
//   - cell stride 40 shorts: 16B-granule class = (5*pos + c8) mod 8 -> exactly
//     8 lanes/class for both staging writes and A-reads (conflict-free minimum)
//   - launch_bounds(256,3): 12 waves/CU, 3 barrier domains overlap stage/compute

#define CIN   64
#define COUT  64
#define HH    128
#define WW    128

typedef __attribute__((ext_vector_type(8)))  short bf16x8;   // 4 VGPRs
typedef __attribute__((ext_vector_type(4)))  float f32x4;
typedef __attribute__((ext_vector_type(16))) float f32x16;   // 32x32 acc
typedef __attribute__((ext_vector_type(4)))  unsigned int u32x4;

__device__ __forceinline__ unsigned short f2bf(float f) {
  unsigned int u = __float_as_uint(f);
  u = (u + 0x7fffu + ((u >> 16) & 1u)) >> 16;   // RNE
  return (unsigned short)u;
}

// ---------------------------------------------------------------------------
// W4[o][c][tap(r,s)] = sum_k w[o,c,k]*cy_k(r-iy_k)*cx_k(s-ix_k).
//   wb[(((g*2+h8)*16 + rs8*2 + ni)*64 + lane)*8 + j]
// consuming lane: o = ni*32 + (lane&31), ch = g*16 + (lane>>5)*8 + j, tap=h8*8+rs8.
// (verified in v4: absmax 0.0156)
// ---------------------------------------------------------------------------
__global__ void make_wb(const float* __restrict__ wgt,
                        const float* __restrict__ off,
                        unsigned short* __restrict__ wb)
{
  int id = blockIdx.x * 64 + threadIdx.x;       // 4096 = 64*64
  int o = id >> 6, c = id & 63;
  float W16[16];
  #pragma unroll
  for (int i = 0; i < 16; ++i) W16[i] = 0.f;
  for (int k = 0; k < 9; ++k) {
    float dy = off[2*k], dx = off[2*k+1];
    float fyf = floorf(dy), fxf = floorf(dx);
    int   iy = (int)fyf,   ix = (int)fxf;       // in {0,1,2}
    float fy = dy - fyf,   fx = dx - fxf;
    float wk = wgt[(o*CIN + c)*9 + k];
    W16[(iy  )*4 + ix  ] += wk * (1.f-fy)*(1.f-fx);
    W16[(iy  )*4 + ix+1] += wk * (1.f-fy)*fx;
    W16[(iy+1)*4 + ix  ] += wk * fy*(1.f-fx);
    W16[(iy+1)*4 + ix+1] += wk * fy*fx;
  }
  int g = c >> 4, half = (c >> 3) & 1, j = c & 7;
  int ni = o >> 5, l31 = o & 31;
  int lane = half*32 + l31;
  for (int tap = 0; tap < 16; ++tap) {
    int h8 = tap >> 3, rs8 = tap & 7;
    wb[(size_t)((((g*2 + h8)*16) + rs8*2 + ni)*64 + lane)*8 + j] = f2bf(W16[tap]);
  }
}

// ---------------------------------------------------------------------------
constexpr int CELLS = 40;  // shorts per (row,pos) cell: 32 ch + 8 pad = 80 B
constexpr int LPOS  = 68;  // pos = gx - (x0-1), 0..66 used

__global__ __launch_bounds__(256, 3)          // 3 blocks/CU target
void conv_mfma(const float* __restrict__ x,
               const unsigned short* __restrict__ wb,
               float* __restrict__ out)
{
  __shared__ unsigned short lt[7 * LPOS * CELLS];   // 38080 B

  const int wg = blockIdx.x;                  // 512 = 8 b * 32 ybands * 2 xh
  const int b  = wg >> 6;
  const int y0 = ((wg >> 1) & 31) * 4;
  const int x0 = (wg & 1) * 64;
  const int t  = threadIdx.x;
  const int lane = t & 63;
  const int wave = t >> 6;                    // 0..3 = output row
  const int l31  = lane & 31;
  const int half = lane >> 5;

  f32x16 acc[2][2];
  #pragma unroll
  for (int xh = 0; xh < 2; ++xh)
    #pragma unroll
    for (int ni = 0; ni < 2; ++ni)
      acc[xh][ni] = (f32x16)(0.f);

  const unsigned short* wl = wb + lane*8;

  #pragma unroll
  for (int p = 0; p < 2; ++p) {               // channel pass: ch in [32p, 32p+32)
    if (p) __syncthreads();                   // pass-0 reads complete

    // ---- stage 7 rows x 68 pos x 32 ch (this pass), bf16 ----
    for (int id = t; id < 28 * LPOS; id += 256) {
      int cg  = id / LPOS;                    // row*4 + c8
      int pos = id - cg * LPOS;
      int row = cg >> 2;                      // 0..6
      int c8  = cg & 3;                       // 8-ch chunk within pass
      int gy  = y0 + row - 1;
      int gx  = x0 + pos - 1;
      bool ok = ((unsigned)gy < (unsigned)HH) && ((unsigned)gx < (unsigned)WW);
      int sgy = ok ? gy : 0, sgx = ok ? gx : 0;
      float sc = ok ? 1.f : 0.f;
      const float* ps = x + ((size_t)(b*CIN + p*32 + c8*8)*HH + sgy)*WW + sgx;
      float v[8];
      #pragma unroll
      for (int cc = 0; cc < 8; ++cc) v[cc] = ps[(size_t)cc*HH*WW] * sc;
      unsigned int pk[4];
      #pragma unroll
      for (int i = 0; i < 4; ++i)
        pk[i] = (unsigned int)f2bf(v[2*i]) | ((unsigned int)f2bf(v[2*i+1]) << 16);
      *(u32x4*)&lt[(row*LPOS + pos)*CELLS + c8*8] = *(u32x4*)pk;
    }
    __syncthreads();

    // ---- compute: 16 pair-iters (g2,h8,q4), 2 taps each, B double-buffered ----
    bf16x8 bcur[4], bnxt[4];
    {
      const int g = p*2;                       // ki = 0: g2=0,h8=0,q4=0
      #pragma unroll
      for (int dt = 0; dt < 2; ++dt)
        #pragma unroll
        for (int ni = 0; ni < 2; ++ni)
          bcur[dt*2+ni] = *(const bf16x8*)(wl + (size_t)(((g*2 + 0)*16) + dt*2 + ni)*512);
    }
    #pragma unroll
    for (int ki = 0; ki < 16; ++ki) {
      if (ki < 15) {
        const int kn = ki + 1;
        const int g2n = kn >> 3, h8n = (kn >> 2) & 1, q4n = kn & 3;
        const int gn = p*2 + g2n;
        #pragma unroll
        for (int dt = 0; dt < 2; ++dt)
          #pragma unroll
          for (int ni = 0; ni < 2; ++ni)
            bnxt[dt*2+ni] = *(const bf16x8*)(wl + (size_t)(((gn*2 + h8n)*16) + (q4n*2+dt)*2 + ni)*512);
      }
      const int g2 = ki >> 3, h8 = (ki >> 2) & 1, q4 = ki & 3;
      #pragma unroll
      for (int dt = 0; dt < 2; ++dt) {
        const int tap = h8*8 + q4*2 + dt;
        const int r = tap >> 2, sx = tap & 3;
        #pragma unroll
        for (int xh = 0; xh < 2; ++xh) {
          bf16x8 afr = *(const bf16x8*)
            &lt[((wave + r)*LPOS + (xh*32 + l31 + sx))*CELLS + g2*16 + half*8];
          acc[xh][0] = __builtin_amdgcn_mfma_f32_32x32x16_bf16(afr, bcur[dt*2+0], acc[xh][0], 0, 0, 0);
          acc[xh][1] = __builtin_amdgcn_mfma_f32_32x32x16_bf16(afr, bcur[dt*2+1], acc[xh][1], 0, 0, 0);
        }
      }
      #pragma unroll
      for (int i = 0; i < 4; ++i) bcur[i] = bnxt[i];
    }
  }

  // ---- epilogue: D col = o (lane&31), row = (reg&3) + 8*(reg>>2) + 4*half ----
  const int y = y0 + wave;
  #pragma unroll
  for (int xh = 0; xh < 2; ++xh) {
    #pragma unroll
    for (int ni = 0; ni < 2; ++ni) {
      int o = ni*32 + l31;
      float* dst = out + (((size_t)(b*COUT + o))*HH + y)*WW + x0 + xh*32 + 4*half;
      #pragma unroll
      for (int rg = 0; rg < 4; ++rg) {
        f32x4 v = (f32x4){acc[xh][ni][4*rg+0], acc[xh][ni][4*rg+1],
                          acc[xh][ni][4*rg+2], acc[xh][ni][4*rg+3]};
        *(f32x4*)(dst + 8*rg) = v;
      }
    }
  }
}

// ---------------------------------------------------------------------------
extern "C" void kernel_launch(void* const* d_in, const int* in_sizes, int n_in,
                              void* d_out, int out_size, void* d_ws, size_t ws_size,
                              hipStream_t stream)
{
  const float* x   = (const float*)d_in[0];   // [8,64,128,128] fp32
  const float* wgt = (const float*)d_in[1];   // [64,64,9] fp32
  const float* off = (const float*)d_in[2];   // [9,2] fp32
  float* out = (float*)d_out;                 // [8,64,128,128] fp32
  unsigned short* wb = (unsigned short*)d_ws; // 128 KB chunked weights

  make_wb<<<64, 64, 0, stream>>>(wgt, off, wb);
  conv_mfma<<<512, 256, 0, stream>>>(x, wb, out);
}

// Round 6
// 110.431 us; speedup vs baseline: 1.0579x; 1.0518x over previous
//
#include <hip/hip_runtime.h>

// B=8, Cin=64, H=W=128, Cout=64, 9 bilinear taps at (i+0.4, j+0.4) == exact 4x4
// conv with zero pad. Implicit GEMM, bf16 MFMA 32x32x16.
//
// v6: MLP-first restructure of v5 (same verified math/layouts).
//   - staging fully unrolled w/ pow2 item map: 7 exact iters (28cg x 64pos)
//     + 1 masked edge step -> ~60 independent global loads in flight/thread
//   - cross-pass pipeline: double-buffered LDS (2x38080B, still 2 blocks/CU);
//     pass-1 loads issued BEFORE pass-0 compute, packed/written after
//   - B-fragment prefetch distance 2 (3-slot rotation)
//   - XCD=batch swizzle (wg&7): halo re-reads hit same XCD L2

#define CIN   64
#define COUT  64
#define HH    128
#define WW    128

typedef __attribute__((ext_vector_type(8)))  short bf16x8;   // 4 VGPRs
typedef __attribute__((ext_vector_type(4)))  float f32x4;
typedef __attribute__((ext_vector_type(16))) float f32x16;   // 32x32 acc
typedef __attribute__((ext_vector_type(4)))  unsigned int u32x4;

__device__ __forceinline__ unsigned short f2bf(float f) {
  unsigned int u = __float_as_uint(f);
  u = (u + 0x7fffu + ((u >> 16) & 1u)) >> 16;   // RNE
  return (unsigned short)u;
}

// ---------------------------------------------------------------------------
// W4[o][c][tap(r,s)] = sum_k w[o,c,k]*cy_k(r-iy_k)*cx_k(s-ix_k).
//   wb[(((g*2+h8)*16) + rs8*2 + ni)*64 + lane)*8 + j]
// lane: o = ni*32 + (lane&31), ch = g*16 + (lane>>5)*8 + j, tap = h8*8 + rs8.
// (verified v4/v5: absmax 0.0156)
// ---------------------------------------------------------------------------
__global__ void make_wb(const float* __restrict__ wgt,
                        const float* __restrict__ off,
                        unsigned short* __restrict__ wb)
{
  int id = blockIdx.x * 64 + threadIdx.x;       // 4096 = 64*64
  int o = id >> 6, c = id & 63;
  float W16[16];
  #pragma unroll
  for (int i = 0; i < 16; ++i) W16[i] = 0.f;
  for (int k = 0; k < 9; ++k) {
    float dy = off[2*k], dx = off[2*k+1];
    float fyf = floorf(dy), fxf = floorf(dx);
    int   iy = (int)fyf,   ix = (int)fxf;       // in {0,1,2}
    float fy = dy - fyf,   fx = dx - fxf;
    float wk = wgt[(o*CIN + c)*9 + k];
    W16[(iy  )*4 + ix  ] += wk * (1.f-fy)*(1.f-fx);
    W16[(iy  )*4 + ix+1] += wk * (1.f-fy)*fx;
    W16[(iy+1)*4 + ix  ] += wk * fy*(1.f-fx);
    W16[(iy+1)*4 + ix+1] += wk * fy*fx;
  }
  int g = c >> 4, half = (c >> 3) & 1, j = c & 7;
  int ni = o >> 5, l31 = o & 31;
  int lane = half*32 + l31;
  for (int tap = 0; tap < 16; ++tap) {
    int h8 = tap >> 3, rs8 = tap & 7;
    wb[(size_t)((((g*2 + h8)*16) + rs8*2 + ni)*64 + lane)*8 + j] = f2bf(W16[tap]);
  }
}

// ---------------------------------------------------------------------------
constexpr int CELLS = 40;   // shorts per (row,pos) cell: 32 ch + 8 pad = 80 B
constexpr int LPOS  = 68;   // pos = gx - (x0-1), 0..66 used
constexpr int BUFS  = 7 * LPOS * CELLS;   // 19040 shorts = 38080 B per buffer

__global__ __launch_bounds__(256, 2)
void conv_mfma(const float* __restrict__ x,
               const unsigned short* __restrict__ wb,
               float* __restrict__ out)
{
  __shared__ unsigned short lt[2 * BUFS];   // 76160 B -> 2 blocks/CU

  const int wg = blockIdx.x;                // 512
  const int b  = wg & 7;                    // XCD = batch (wg%8 round-robin)
  const int i6 = wg >> 3;                   // 0..63
  const int y0 = (i6 >> 1) * 4;
  const int x0 = (i6 & 1) * 64;
  const int t  = threadIdx.x;
  const int lane = t & 63;
  const int wave = t >> 6;                  // 0..3 = output row
  const int l31  = lane & 31;
  const int half = lane >> 5;

  // edge-step coords (items: cg = t>>2 in 0..27, pos = 64 + (t&3))
  const int ecg  = t >> 2;
  const int epos = 64 + (t & 3);
  const bool eact = (t < 112);

  // ---- staging helpers (pow2 map: id = it*256+t, cg = id>>6, pos = id&63) ----
  auto stage_issue = [&](int p, float (&v)[8][8]) {
    #pragma unroll
    for (int it = 0; it < 7; ++it) {
      int id  = it*256 + t;
      int cg  = id >> 6;                    // 0..27 = row*4 + c8
      int pos = id & 63;
      int row = cg >> 2, c8 = cg & 3;
      int gy  = y0 + row - 1;
      int gx  = x0 + pos - 1;
      bool ok = ((unsigned)gy < (unsigned)HH) && ((unsigned)gx < (unsigned)WW);
      const float* ps = x + ((size_t)(b*CIN + p*32 + c8*8)*HH + (ok ? gy : 0))*WW + (ok ? gx : 0);
      float sc = ok ? 1.f : 0.f;
      #pragma unroll
      for (int cc = 0; cc < 8; ++cc) v[it][cc] = ps[(size_t)cc*HH*WW] * sc;
    }
    { // edge columns 64..67
      int row = ecg >> 2, c8 = ecg & 3;
      int gy  = y0 + row - 1;
      int gx  = x0 + epos - 1;
      bool ok = eact && ((unsigned)gy < (unsigned)HH) && ((unsigned)gx < (unsigned)WW);
      const float* ps = x + ((size_t)(b*CIN + p*32 + c8*8)*HH + (ok ? gy : 0))*WW + (ok ? gx : 0);
      float sc = ok ? 1.f : 0.f;
      #pragma unroll
      for (int cc = 0; cc < 8; ++cc) v[7][cc] = ps[(size_t)cc*HH*WW] * sc;
    }
  };

  auto stage_write = [&](float (&v)[8][8], unsigned short* base) {
    #pragma unroll
    for (int it = 0; it < 7; ++it) {
      int id  = it*256 + t;
      int cg  = id >> 6;
      int pos = id & 63;
      int row = cg >> 2, c8 = cg & 3;
      unsigned int pk[4];
      #pragma unroll
      for (int i = 0; i < 4; ++i)
        pk[i] = (unsigned int)f2bf(v[it][2*i]) | ((unsigned int)f2bf(v[it][2*i+1]) << 16);
      *(u32x4*)&base[(row*LPOS + pos)*CELLS + c8*8] = *(u32x4*)pk;
    }
    if (eact) {
      int row = ecg >> 2, c8 = ecg & 3;
      unsigned int pk[4];
      #pragma unroll
      for (int i = 0; i < 4; ++i)
        pk[i] = (unsigned int)f2bf(v[7][2*i]) | ((unsigned int)f2bf(v[7][2*i+1]) << 16);
      *(u32x4*)&base[(row*LPOS + epos)*CELLS + c8*8] = *(u32x4*)pk;
    }
  };

  f32x16 acc[2][2];
  #pragma unroll
  for (int xh = 0; xh < 2; ++xh)
    #pragma unroll
    for (int ni = 0; ni < 2; ++ni)
      acc[xh][ni] = (f32x16)(0.f);

  const unsigned short* wl = wb + lane*8;

  auto loadB = [&](int p, int ki, bf16x8 (&dst)[4]) {
    int g2 = ki >> 3, h8 = (ki >> 2) & 1, q4 = ki & 3;
    int g = p*2 + g2;
    #pragma unroll
    for (int dt = 0; dt < 2; ++dt)
      #pragma unroll
      for (int ni = 0; ni < 2; ++ni)
        dst[dt*2+ni] = *(const bf16x8*)(wl + (size_t)(((g*2 + h8)*16) + (q4*2+dt)*2 + ni)*512);
  };

  auto compute = [&](int p, const unsigned short* base) {
    bf16x8 bq[3][4];
    loadB(p, 0, bq[0]);
    loadB(p, 1, bq[1]);
    #pragma unroll
    for (int ki = 0; ki < 16; ++ki) {
      if (ki < 14) loadB(p, ki + 2, bq[(ki + 2) % 3]);
      const int g2 = ki >> 3, h8 = (ki >> 2) & 1, q4 = ki & 3;
      #pragma unroll
      for (int dt = 0; dt < 2; ++dt) {
        const int tap = h8*8 + q4*2 + dt;
        const int r = tap >> 2, sx = tap & 3;
        #pragma unroll
        for (int xh = 0; xh < 2; ++xh) {
          bf16x8 afr = *(const bf16x8*)
            &base[((wave + r)*LPOS + (xh*32 + l31 + sx))*CELLS + g2*16 + half*8];
          acc[xh][0] = __builtin_amdgcn_mfma_f32_32x32x16_bf16(afr, bq[ki % 3][dt*2+0], acc[xh][0], 0, 0, 0);
          acc[xh][1] = __builtin_amdgcn_mfma_f32_32x32x16_bf16(afr, bq[ki % 3][dt*2+1], acc[xh][1], 0, 0, 0);
        }
      }
    }
  };

  // ---- pipelined body ----
  float v0[8][8];
  stage_issue(0, v0);
  stage_write(v0, lt);
  __syncthreads();

  float v1[8][8];
  stage_issue(1, v1);         // pass-1 loads in flight during pass-0 compute
  compute(0, lt);
  stage_write(v1, lt + BUFS);
  __syncthreads();

  compute(1, lt + BUFS);

  // ---- epilogue: D col = o (lane&31), row = (reg&3) + 8*(reg>>2) + 4*half ----
  const int y = y0 + wave;
  #pragma unroll
  for (int xh = 0; xh < 2; ++xh) {
    #pragma unroll
    for (int ni = 0; ni < 2; ++ni) {
      int o = ni*32 + l31;
      float* dst = out + (((size_t)(b*COUT + o))*HH + y)*WW + x0 + xh*32 + 4*half;
      #pragma unroll
      for (int rg = 0; rg < 4; ++rg) {
        f32x4 v = (f32x4){acc[xh][ni][4*rg+0], acc[xh][ni][4*rg+1],
                          acc[xh][ni][4*rg+2], acc[xh][ni][4*rg+3]};
        *(f32x4*)(dst + 8*rg) = v;
      }
    }
  }
}

// ---------------------------------------------------------------------------
extern "C" void kernel_launch(void* const* d_in, const int* in_sizes, int n_in,
                              void* d_out, int out_size, void* d_ws, size_t ws_size,
                              hipStream_t stream)
{
  const float* x   = (const float*)d_in[0];   // [8,64,128,128] fp32
  const float* wgt = (const float*)d_in[1];   // [64,64,9] fp32
  const float* off = (const float*)d_in[2];   // [9,2] fp32
  float* out = (float*)d_out;                 // [8,64,128,128] fp32
  unsigned short* wb = (unsigned short*)d_ws; // 128 KB chunked weights

  make_wb<<<64, 64, 0, stream>>>(wgt, off, wb);
  conv_mfma<<<512, 256, 0, stream>>>(x, wb, out);
}